// Round 1
// baseline (290.624 us; speedup 1.0000x reference)
//
#include <hip/hip_runtime.h>
#include <hip/hip_bf16.h>
#include <math.h>

#define B_ 4
#define N_ 2048
#define D_ 1024
#define H_ 16
#define HD_ 64
#define SCALE_ 0.015625f   // 1/HD
#define MD_ ((size_t)B_ * N_ * D_)   // 8388608
#define DD_ ((size_t)D_ * D_)        // 1048576
#define BHSZ_ ((size_t)N_ * HD_)     // 131072 elems per (b,h) frag slab
// folded into q at RoPE: SCALE * log2(e)
#define QSC_ 0.0225421143f

typedef __hip_bfloat16 bf16;
typedef __attribute__((ext_vector_type(8))) __bf16 bf16x8;
typedef __attribute__((ext_vector_type(4))) float f32x4;
typedef __attribute__((ext_vector_type(16))) float f32x16;

__device__ __forceinline__ float b2f(bf16 x) { return __bfloat162float(x); }
__device__ __forceinline__ bf16 f2b(float x) { return __float2bfloat16(x); }

// exact (RNE) pack of two floats to bf16 pair (elem0 low)
__device__ __forceinline__ unsigned int pk2(float a, float b) {
  union { bf16 h[2]; unsigned int u; } t;
  t.h[0] = f2b(a); t.h[1] = f2b(b);
  return t.u;
}
// truncating pack (cheap; for P fragments only, e >= 0)
__device__ __forceinline__ unsigned int pk2t(float a, float b) {
  return (__float_as_uint(a) >> 16) | (__float_as_uint(b) & 0xffff0000u);
}

// async global->LDS, 16 bytes per lane
__device__ __forceinline__ void gl_lds16(const bf16* g, bf16* l) {
  __builtin_amdgcn_global_load_lds(
      (const __attribute__((address_space(1))) void*)g,
      (__attribute__((address_space(3))) void*)l, 16, 0, 0);
}

// raw barrier with IR-level memory fences (NO vmcnt drain — that was the
// m97-structure stall; vmcnt is counted explicitly at tile boundaries)
__device__ __forceinline__ void fbar() {
  asm volatile("" ::: "memory");
  __builtin_amdgcn_s_barrier();
  asm volatile("" ::: "memory");
}

#define MFMA16(a, b, c) __builtin_amdgcn_mfma_f32_16x16x32_bf16((a), (b), (c), 0, 0, 0)

// ---------------------------------------------------------------------------
// Fused fp32 -> bf16 conversion of x, Wq, Wk, Wv, Wo (one launch).
// ---------------------------------------------------------------------------
__global__ __launch_bounds__(256) void cvt_all(
    const float* __restrict__ x,  const float* __restrict__ wq,
    const float* __restrict__ wk, const float* __restrict__ wv,
    const float* __restrict__ wo, bf16* __restrict__ xb,
    bf16* __restrict__ wb)
{
  const int blk = blockIdx.x;
  const float* s; bf16* d; int i;
  if (blk < 4096)      { s = x;  d = xb;           i = blk; }
  else if (blk < 4608) { s = wq; d = wb;           i = blk - 4096; }
  else if (blk < 5120) { s = wk; d = wb + DD_;     i = blk - 4608; }
  else if (blk < 5632) { s = wv; d = wb + 2 * DD_; i = blk - 5120; }
  else                 { s = wo; d = wb + 3 * DD_; i = blk - 5632; }
  int e = (i * 256 + threadIdx.x) * 8;
  float4 a = *reinterpret_cast<const float4*>(s + e);
  float4 b = *reinterpret_cast<const float4*>(s + e + 4);
  bf16 t[8] = {f2b(a.x), f2b(a.y), f2b(a.z), f2b(a.w),
               f2b(b.x), f2b(b.y), f2b(b.z), f2b(b.w)};
  *reinterpret_cast<int4*>(d + e) = *reinterpret_cast<const int4*>(t);
}

// ---------------------------------------------------------------------------
// 8-phase deep-pipelined MFMA GEMM: C[M,N] = A[M,K] @ W[N,K]^T, bf16 in,
// fp32 accumulate. Tile 256x128, BK=64 split in two 32-col k-halves, 8 waves
// (2M x 4N), 512 threads, 1 block/CU (96 KB LDS).
//
// Per K-tile: 4 phases of {ds_read frag subtile; issue 1 half-tile of
// global_load_lds; raw barrier; setprio(1); 8 MFMA; setprio(0); raw barrier}.
// One counted s_waitcnt vmcnt(3) per K-tile (next tile's kh0 stream stays in
// flight across the barrier) — never vmcnt(0) in steady state.
//
// Slot lifetimes (group t, buffer b = t&1):
//   kh0(b) read P1,P2 -> re-staged (tile t+2) at P3,P4    (>=1 barrier after free)
//   kh1(b^1) freed end of prev group -> staged (tile t+1) at P1,P2
// vmcnt(3) at end of P4 guarantees tile t+1 fully landed with exactly the
// 3 P3/P4 issues (tile t+2 kh0) outstanding.
//
// Staging swizzle carried over from the verified 128^2 kernel: chunk = 16
// rows x 32 cols, lane i fetches global slot (i&3)^((i>>3)&3) of row i>>2;
// reader: phys slot = quad ^ ((lm>>1)&3)  (2-way bank-aliased = free).
//
// MODE 0: fused QKV epilogue — frag-tiled Q/K/V exactly as before.
// MODE 1: fp32 output + bias.
// ---------------------------------------------------------------------------
template <int MODE>
__global__ __launch_bounds__(512, 2) void mgemm8(
    const bf16* __restrict__ A, const bf16* __restrict__ W,
    const float* __restrict__ bias, void* __restrict__ Cv,
    int M, int N, int K)
{
  __shared__ bf16 As[2 * 2 * 256 * 32];   // [buf][khalf][256 rows][32 cols] 64 KB
  __shared__ bf16 Ws[2 * 2 * 128 * 32];   // [buf][khalf][128 rows][32 cols] 32 KB

  const int tid  = threadIdx.x;
  const int w    = tid >> 6;          // wave 0..7
  const int lane = tid & 63;
  const int wm   = w >> 2;            // 0..1: M half (128 rows)
  const int wn   = w & 3;             // 0..3: N quarter (32 cols)
  const int lm   = lane & 15;
  const int quad = lane >> 4;

  // bijective XCD swizzle (nwg % 8 == 0 for both grids)
  const int wgid = (blockIdx.x & 7) * ((int)gridDim.x >> 3) + ((int)blockIdx.x >> 3);
  const int nbn  = N >> 7;
  const int bn   = (wgid % nbn) * 128;
  const int bm   = (wgid / nbn) * 256;

  // staging pattern
  const int srow = lane >> 2;                        // 0..15 within chunk
  const int scol = ((lane & 3) ^ ((lane >> 3) & 3)) * 8;
  const int rsw  = (quad ^ ((lm >> 1) & 3)) * 8;

  const int NT = K >> 6;              // 16

  f32x4 acc[8][2] = {};

  auto ASL = [&](int b, int kh) -> bf16* { return &As[(b * 2 + kh) * 8192]; };
  auto WSL = [&](int b, int kh) -> bf16* { return &Ws[(b * 2 + kh) * 4096]; };

  // A k-half = 256x32 = 16 chunks of (16 rows x 32 cols); 2 issues/wave
  auto stA = [&](int b, int kh, int t) {
    size_t k = (size_t)t * 64 + kh * 32;
#pragma unroll
    for (int j = 0; j < 2; ++j) {
      int c = w * 2 + j;
      gl_lds16(A + (size_t)(bm + c * 16 + srow) * K + k + scol,
               ASL(b, kh) + c * 512);
    }
  };
  // W k-half = 128x32 = 8 chunks; 1 issue/wave
  auto stB = [&](int b, int kh, int t) {
    size_t k = (size_t)t * 64 + kh * 32;
    gl_lds16(W + (size_t)(bn + w * 16 + srow) * K + k + scol,
             WSL(b, kh) + w * 512);
  };

  auto rdA = [&](const bf16* slab, int mi) -> bf16x8 {
    return *reinterpret_cast<const bf16x8*>(
        slab + (wm * 128 + mi * 16 + lm) * 32 + rsw);
  };
  auto rdB = [&](const bf16* slab, int ni) -> bf16x8 {
    return *reinterpret_cast<const bf16x8*>(
        slab + (wn * 32 + ni * 16 + lm) * 32 + rsw);
  };

  // prologue: tile0 kh0+kh1, tile1 kh0  (9 loads/wave); wait so tile0 landed,
  // tile1-kh0's 3 loads stay in flight.
  stA(0, 0, 0); stB(0, 0, 0);
  stA(0, 1, 0); stB(0, 1, 0);
  stA(1, 0, 1); stB(1, 0, 1);
  asm volatile("s_waitcnt vmcnt(3)" ::: "memory");
  __builtin_amdgcn_s_barrier();
  asm volatile("" ::: "memory");

#define GROUP(T, S1, S2, WN) do {                                             \
    const int b_ = (T) & 1;                                                   \
    const bf16* A0 = ASL(b_, 0); const bf16* A1 = ASL(b_, 1);                 \
    const bf16* W0 = WSL(b_, 0); const bf16* W1 = WSL(b_, 1);                 \
    bf16x8 xa[4], yb[2];                                                      \
    /* P1: kh0, mi 0-3 + B; stage A-kh1(t+1) */                               \
    _Pragma("unroll") for (int i = 0; i < 4; ++i) xa[i] = rdA(A0, i);         \
    _Pragma("unroll") for (int i = 0; i < 2; ++i) yb[i] = rdB(W0, i);         \
    if (S1) stA(b_ ^ 1, 1, (T) + 1);                                          \
    fbar();                                                                   \
    __builtin_amdgcn_s_setprio(1);                                            \
    _Pragma("unroll") for (int i = 0; i < 4; ++i) {                           \
      acc[i][0] = MFMA16(xa[i], yb[0], acc[i][0]);                            \
      acc[i][1] = MFMA16(xa[i], yb[1], acc[i][1]);                            \
    }                                                                         \
    __builtin_amdgcn_s_setprio(0);                                            \
    fbar();                                                                   \
    /* P2: kh0, mi 4-7 (reuse yb); stage B-kh1(t+1) */                        \
    _Pragma("unroll") for (int i = 0; i < 4; ++i) xa[i] = rdA(A0, 4 + i);     \
    if (S1) stB(b_ ^ 1, 1, (T) + 1);                                          \
    fbar();                                                                   \
    __builtin_amdgcn_s_setprio(1);                                            \
    _Pragma("unroll") for (int i = 0; i < 4; ++i) {                           \
      acc[4 + i][0] = MFMA16(xa[i], yb[0], acc[4 + i][0]);                    \
      acc[4 + i][1] = MFMA16(xa[i], yb[1], acc[4 + i][1]);                    \
    }                                                                         \
    __builtin_amdgcn_s_setprio(0);                                            \
    fbar();                                                                   \
    /* P3: kh1, mi 0-3 + B; stage A-kh0(t+2) (kh0 freed end of P2) */         \
    _Pragma("unroll") for (int i = 0; i < 4; ++i) xa[i] = rdA(A1, i);         \
    _Pragma("unroll") for (int i = 0; i < 2; ++i) yb[i] = rdB(W1, i);         \
    if (S2) stA(b_, 0, (T) + 2);                                              \
    fbar();                                                                   \
    __builtin_amdgcn_s_setprio(1);                                            \
    _Pragma("unroll") for (int i = 0; i < 4; ++i) {                           \
      acc[i][0] = MFMA16(xa[i], yb[0], acc[i][0]);                            \
      acc[i][1] = MFMA16(xa[i], yb[1], acc[i][1]);                            \
    }                                                                         \
    __builtin_amdgcn_s_setprio(0);                                            \
    fbar();                                                                   \
    /* P4: kh1, mi 4-7; stage B-kh0(t+2); tile-boundary counted vmcnt */      \
    _Pragma("unroll") for (int i = 0; i < 4; ++i) xa[i] = rdA(A1, 4 + i);     \
    if (S2) stB(b_, 0, (T) + 2);                                              \
    fbar();                                                                   \
    __builtin_amdgcn_s_setprio(1);                                            \
    _Pragma("unroll") for (int i = 0; i < 4; ++i) {                           \
      acc[4 + i][0] = MFMA16(xa[i], yb[0], acc[4 + i][0]);                    \
      acc[4 + i][1] = MFMA16(xa[i], yb[1], acc[4 + i][1]);                    \
    }                                                                         \
    __builtin_amdgcn_s_setprio(0);                                            \
    if ((WN) == 3)      asm volatile("s_waitcnt vmcnt(3)" ::: "memory");      \
    else if ((WN) == 0) asm volatile("s_waitcnt vmcnt(0)" ::: "memory");      \
    fbar();                                                                   \
  } while (0)

  for (int t = 0; t < NT - 2; ++t) GROUP(t, true, true, 3);
  GROUP(NT - 2, true, false, 0);
  GROUP(NT - 1, false, false, -1);
#undef GROUP

  // epilogue
#pragma unroll
  for (int mi = 0; mi < 8; ++mi) {
#pragma unroll
    for (int r = 0; r < 4; ++r) {
      int row = bm + wm * 128 + mi * 16 + quad * 4 + r;
#pragma unroll
      for (int ni = 0; ni < 2; ++ni) {
        int col = bn + wn * 32 + ni * 16 + lm;
        float v = acc[mi][ni][r];
        if (MODE == 1) {
          v += bias[col];
          reinterpret_cast<float*>(Cv)[(size_t)row * N + col] = v;
        } else {
          int reg = col >> 10;            // 0=q, 1=k, 2=v
          int cc  = col & 1023;
          int bb  = row >> 11;            // N_ == 2048
          int n   = row & (N_ - 1);
          int hh  = cc >> 6;
          int dd  = cc & 63;
          if (reg < 2) {
            // frag-tiled F[bh][t32][s][hi][m][8]: d = 16s+8hi+j, m = n&31
            int t32 = n >> 5, m = n & 31;
            int s = dd >> 4, hb = (dd >> 3) & 1, j = dd & 7;
            reinterpret_cast<bf16*>(Cv)[(size_t)reg * MD_ +
                (size_t)(bb * H_ + hh) * BHSZ_ +
                (size_t)t32 * 2048 + s * 512 + hb * 256 + m * 8 + j] = f2b(v);
          } else {
            // Vf[bh][t32][hf][hi][hd][8]; key = 32*t32 + 16*hf + 8*hi + j
            int t32 = n >> 5, kk = n & 31;
            int hf = kk >> 4, hb = (kk >> 3) & 1, j = kk & 7;
            reinterpret_cast<bf16*>(Cv)[2 * MD_ +
                (size_t)(bb * H_ + hh) * BHSZ_ +
                (size_t)t32 * 2048 + hf * 1024 + hb * 512 + dd * 8 + j] = f2b(v);
          }
        }
      }
    }
  }
}

// ---------------------------------------------------------------------------
// In-place RoPE on frag-tiled Q and K (one launch). Each thread owns one
// 16B block = (bh, t32, s, hi, m, j=0..7) -> 4 interleaved pairs, all with
// n = 32*t32 + m, i = 8s + 4hi + p. Fully coalesced 16B r/w.
// Q half additionally folds QSC_ (= SCALE * log2e).
// ---------------------------------------------------------------------------
__global__ __launch_bounds__(256) void rope_inplace(bf16* __restrict__ qf,
                                                    bf16* __restrict__ kf)
{
  const int half = blockIdx.x >> 12;        // 0 = q, 1 = k
  const int blk  = blockIdx.x & 4095;
  bf16* base = half ? kf : qf;
  const float LN_THETA = 9.210340371976184f;

  size_t e = ((size_t)blk * 256 + threadIdx.x) * 8;
  int within = (int)(e & (BHSZ_ - 1));
  int t32 = within >> 11;
  int rem = within & 2047;
  int s  = rem >> 9;
  int hb = (rem >> 8) & 1;
  int m  = (rem >> 3) & 31;
  int n  = t32 * 32 + m;

  uint4 raw = *reinterpret_cast<const uint4*>(base + e);
  unsigned int pr[4] = {raw.x, raw.y, raw.z, raw.w};
  unsigned int outw[4];
#pragma unroll
  for (int p = 0; p < 4; ++p) {
    int i = s * 8 + hb * 4 + p;
    float inv = __expf(-((float)(2 * i) / (float)HD_) * LN_THETA);
    float ang = (float)n * inv;
    float sv, cv;
    sincosf(ang, &sv, &cv);
    float a = b2f(((bf16*)&pr[p])[0]);
    float c = b2f(((bf16*)&pr[p])[1]);
    float r0 = a * cv - c * sv;
    float r1 = c * cv + a * sv;
    if (half == 0) { r0 *= QSC_; r1 *= QSC_; }
    outw[p] = pk2(r0, r1);
  }
  uint4 o = {outw[0], outw[1], outw[2], outw[3]};
  *reinterpret_cast<uint4*>(base + e) = o;
}

// ---------------------------------------------------------------------------
// Flash attention v4 (unchanged — verified): transpose formulation
// (S^T = K Q^T, O^T = V^T P^T, mfma_f32_32x32x16_bf16), shift-free softmax,
// 2-way key-split + LDS combine, frag-tiled operands.
// C/D: col=lane&31, row=(reg&3)+8*(reg>>2)+4*(lane>>5)  [m74/m101].
// ---------------------------------------------------------------------------
__global__ __launch_bounds__(128) void fattn4_kernel(
    const bf16* __restrict__ Qf, const bf16* __restrict__ Kf,
    const bf16* __restrict__ Vf, bf16* __restrict__ O)
{
  __shared__ float Ls[32 * 64];
  __shared__ float Ll[64];

  const int wv   = threadIdx.x >> 6;       // key-split half 0/1
  const int lane = threadIdx.x & 63;
  const int blk  = blockIdx.x;             // 0..4095
  const int xcd  = blk & 7;
  const int j    = blk >> 3;               // 0..511
  const int qt   = 63 - (j >> 3);          // big q-tiles dispatched first
  const int bh   = xcd * 8 + (j & 7);      // 8 bh per XCD group
  const int b    = bh >> 4;
  const int h    = bh & 15;
  const int col  = lane & 31;              // q-row / hd-row within frag
  const int hi   = lane >> 5;              // lane half

  const bf16* Qb = Qf + (size_t)bh * BHSZ_ + (size_t)qt * 2048 + hi * 256 + col * 8;
  const bf16* Kb = Kf + (size_t)bh * BHSZ_ + hi * 256 + col * 8;
  const bf16* Vb = Vf + (size_t)bh * BHSZ_ + hi * 512 + col * 8;

  bf16x8 qb[4];
#pragma unroll
  for (int s = 0; s < 4; ++s)
    qb[s] = *reinterpret_cast<const bf16x8*>(Qb + s * 512);

  f32x16 o0 = {}, o1 = {};
  float lsum = 0.f;

  for (int kst = wv; kst <= qt; kst += 2) {
    const bf16* kp = Kb + (size_t)kst * 2048;
    f32x16 st = {};
#pragma unroll
    for (int s = 0; s < 4; ++s) {
      bf16x8 ka = *reinterpret_cast<const bf16x8*>(kp + s * 512);
      st = __builtin_amdgcn_mfma_f32_32x32x16_bf16(ka, qb[s], st, 0, 0, 0);
    }

    float pe[16];
    if (kst == qt) {
#pragma unroll
      for (int r = 0; r < 16; ++r) {
        int koff = (r & 3) + 8 * (r >> 2) + 4 * hi;
        float e = (koff <= col) ? exp2f(st[r]) : 0.f;
        pe[r] = e; lsum += e;
      }
    } else {
#pragma unroll
      for (int r = 0; r < 16; ++r) {
        float e = exp2f(st[r]);
        pe[r] = e; lsum += e;
      }
    }

    const bf16* vp = Vb + (size_t)kst * 2048;
#pragma unroll
    for (int hf = 0; hf < 2; ++hf) {
      unsigned int a0 = pk2t(pe[8 * hf + 0], pe[8 * hf + 1]);
      unsigned int a1 = pk2t(pe[8 * hf + 2], pe[8 * hf + 3]);
      unsigned int b0 = pk2t(pe[8 * hf + 4], pe[8 * hf + 5]);
      unsigned int b1 = pk2t(pe[8 * hf + 6], pe[8 * hf + 7]);
      unsigned int s0 = hi ? a0 : b0;
      unsigned int s1 = hi ? a1 : b1;
      unsigned int r0 = (unsigned int)__shfl_xor((int)s0, 32);
      unsigned int r1 = (unsigned int)__shfl_xor((int)s1, 32);
      union { uint4 u; bf16x8 v; } pb;
      pb.u.x = hi ? r0 : a0;
      pb.u.y = hi ? r1 : a1;
      pb.u.z = hi ? b0 : r0;
      pb.u.w = hi ? b1 : r1;

      bf16x8 v0 = *reinterpret_cast<const bf16x8*>(vp + hf * 1024);
      bf16x8 v1 = *reinterpret_cast<const bf16x8*>(vp + hf * 1024 + 256);
      o0 = __builtin_amdgcn_mfma_f32_32x32x16_bf16(v0, pb.v, o0, 0, 0, 0);
      o1 = __builtin_amdgcn_mfma_f32_32x32x16_bf16(v1, pb.v, o1, 0, 0, 0);
    }
  }

  if (wv == 1) {
#pragma unroll
    for (int r = 0; r < 16; ++r) {
      Ls[r * 64 + lane]        = o0[r];
      Ls[(16 + r) * 64 + lane] = o1[r];
    }
    Ll[lane] = lsum;
  }
  __syncthreads();
  if (wv == 0) {
    float lt = lsum + Ll[lane];
    lt += __shfl_xor(lt, 32);
    float inv = 1.f / lt;
#pragma unroll
    for (int r = 0; r < 16; ++r) {
      o0[r] = (o0[r] + Ls[r * 64 + lane]) * inv;
      o1[r] = (o1[r] + Ls[(16 + r) * 64 + lane]) * inv;
    }
    bf16* Op = O + ((size_t)(b * N_ + 32 * qt + col)) * D_ + h * HD_;
#pragma unroll
    for (int g = 0; g < 4; ++g) {
      uint2 u;
      u.x = pk2(o0[4 * g + 0], o0[4 * g + 1]);
      u.y = pk2(o0[4 * g + 2], o0[4 * g + 3]);
      *reinterpret_cast<uint2*>(Op + 8 * g + 4 * hi) = u;
      u.x = pk2(o1[4 * g + 0], o1[4 * g + 1]);
      u.y = pk2(o1[4 * g + 2], o1[4 * g + 3]);
      *reinterpret_cast<uint2*>(Op + 32 + 8 * g + 4 * hi) = u;
    }
  }
}

// ---------------------------------------------------------------------------
extern "C" void kernel_launch(void* const* d_in, const int* in_sizes, int n_in,
                              void* d_out, int out_size, void* d_ws, size_t ws_size,
                              hipStream_t stream)
{
  const float* x  = (const float*)d_in[0];
  const float* Wq = (const float*)d_in[1];
  const float* Wk = (const float*)d_in[2];
  const float* Wv = (const float*)d_in[3];
  const float* Wo = (const float*)d_in[4];
  const float* bo = (const float*)d_in[5];
  float* out = (float*)d_out;

  const int M = B_ * N_;                    // 8192

  bf16* xb  = (bf16*)d_ws;                  // x bf16; dead after QKV -> ao
  bf16* qf  = xb + MD_;                     // Qf | Kf | Vf contiguous slabs
  bf16* kf  = qf + MD_;
  bf16* vf  = kf + MD_;
  bf16* Wqb = vf + MD_;                     // Wq|Wk|Wv|Wo bf16
  bf16* Wob = Wqb + 3 * DD_;
  bf16* ao  = xb;

  cvt_all<<<6144, 256, 0, stream>>>(x, Wq, Wk, Wv, Wo, xb, Wqb);

  // fused QKV: C[8192, 3072] vs [Wq;Wk;Wv]; writes Qf,Kf,Vf frag-tiled
  // grid = 32 bm-tiles x 24 bn-tiles = 768 blocks (3 exact CU rounds)
  mgemm8<0><<<dim3(768), 512, 0, stream>>>(xb, Wqb, nullptr, qf, M, 3 * D_, D_);

  // in-place RoPE on Qf (with QSC fold) and Kf: 2 * 4096 blocks
  rope_inplace<<<8192, 256, 0, stream>>>(qf, kf);

  // one block (2 key-split waves) per (bh, 32-row q-tile): 4096 blocks
  fattn4_kernel<<<4096, 128, 0, stream>>>(qf, kf, vf, ao);

  // output proj: 32 x 8 = 256 blocks (1 exact CU round)
  mgemm8<1><<<dim3(256), 512, 0, stream>>>(ao, Wob, bo, out, M, D_, D_);
}

// Round 2
// 282.496 us; speedup vs baseline: 1.0288x; 1.0288x over previous
//
#include <hip/hip_runtime.h>
#include <hip/hip_bf16.h>
#include <math.h>

#define B_ 4
#define N_ 2048
#define D_ 1024
#define H_ 16
#define HD_ 64
#define SCALE_ 0.015625f   // 1/HD
#define MD_ ((size_t)B_ * N_ * D_)   // 8388608
#define DD_ ((size_t)D_ * D_)        // 1048576
#define BHSZ_ ((size_t)N_ * HD_)     // 131072 elems per (b,h) frag slab
// folded into q at RoPE: SCALE * log2(e)
#define QSC_ 0.0225421143f

typedef __hip_bfloat16 bf16;
typedef __attribute__((ext_vector_type(8))) __bf16 bf16x8;
typedef __attribute__((ext_vector_type(4))) float f32x4;
typedef __attribute__((ext_vector_type(16))) float f32x16;

__device__ __forceinline__ float b2f(bf16 x) { return __bfloat162float(x); }
__device__ __forceinline__ bf16 f2b(float x) { return __float2bfloat16(x); }

// exact (RNE) pack of two floats to bf16 pair (elem0 low)
__device__ __forceinline__ unsigned int pk2(float a, float b) {
  union { bf16 h[2]; unsigned int u; } t;
  t.h[0] = f2b(a); t.h[1] = f2b(b);
  return t.u;
}
// truncating pack (cheap; for P fragments only, e >= 0)
__device__ __forceinline__ unsigned int pk2t(float a, float b) {
  return (__float_as_uint(a) >> 16) | (__float_as_uint(b) & 0xffff0000u);
}

// async global->LDS, 16 bytes per lane
__device__ __forceinline__ void gl_lds16(const bf16* g, bf16* l) {
  __builtin_amdgcn_global_load_lds(
      (const __attribute__((address_space(1))) void*)g,
      (__attribute__((address_space(3))) void*)l, 16, 0, 0);
}

// raw barrier with compiler-level memory fences (no vmcnt drain; vmcnt is
// counted explicitly)
__device__ __forceinline__ void fbar() {
  asm volatile("" ::: "memory");
  __builtin_amdgcn_s_barrier();
  asm volatile("" ::: "memory");
}

#define MFMA16(a, b, c) __builtin_amdgcn_mfma_f32_16x16x32_bf16((a), (b), (c), 0, 0, 0)

// ---------------------------------------------------------------------------
// Fused fp32 -> bf16 conversion of x, Wq, Wk, Wv, Wo (one launch).
// ---------------------------------------------------------------------------
__global__ __launch_bounds__(256) void cvt_all(
    const float* __restrict__ x,  const float* __restrict__ wq,
    const float* __restrict__ wk, const float* __restrict__ wv,
    const float* __restrict__ wo, bf16* __restrict__ xb,
    bf16* __restrict__ wb)
{
  const int blk = blockIdx.x;
  const float* s; bf16* d; int i;
  if (blk < 4096)      { s = x;  d = xb;           i = blk; }
  else if (blk < 4608) { s = wq; d = wb;           i = blk - 4096; }
  else if (blk < 5120) { s = wk; d = wb + DD_;     i = blk - 4608; }
  else if (blk < 5632) { s = wv; d = wb + 2 * DD_; i = blk - 5120; }
  else                 { s = wo; d = wb + 3 * DD_; i = blk - 5632; }
  int e = (i * 256 + threadIdx.x) * 8;
  float4 a = *reinterpret_cast<const float4*>(s + e);
  float4 b = *reinterpret_cast<const float4*>(s + e + 4);
  bf16 t[8] = {f2b(a.x), f2b(a.y), f2b(a.z), f2b(a.w),
               f2b(b.x), f2b(b.y), f2b(b.z), f2b(b.w)};
  *reinterpret_cast<int4*>(d + e) = *reinterpret_cast<const int4*>(t);
}

// ---------------------------------------------------------------------------
// QKV ring-GEMM: C[8192,3072] = xb @ [Wq;Wk;Wv]^T, frag-tiled epilogue.
// Tile 256x192, BK=32, ring of FOUR LDS K-step buffers (112 KB), 8 waves
// (2M x 4N, per-wave 128x48 = 8x3 frags, 24 MFMA/step), 512 threads.
//
// Key change vs the failed 8-phase port: fragment ds_reads for step T+1 are
// issued DURING step T (ring depth 4 makes the buffer certified-landed one
// full step before use), so LDS latency hides under the 24-MFMA cluster.
// One raw barrier per K-step; counted vmcnt (never 0 in steady state):
//   stage cadence: step T issues stage(T+3);  end-of-T waits "own outstanding
//   <= n" (n = issues/step: waves 0-3 stage 2A+2B=4, waves 4-7 2A+1B=3),
//   certifying step T+2 landed -> step T+1 may read-ahead buf[(T+2)&3].
// Staging/reader chunk XOR swizzle carried over from the verified kernel
// (16x32 chunks; 2-way bank aliasing = free, SQ_LDS_BANK_CONFLICT == 0).
// ---------------------------------------------------------------------------
__global__ __launch_bounds__(512, 2) void qkv_ring(
    const bf16* __restrict__ A, const bf16* __restrict__ W,
    bf16* __restrict__ Cv)
{
  __shared__ bf16 As[4 * 256 * 32];   // 4 ring bufs x 16 KB
  __shared__ bf16 Ws[4 * 192 * 32];   // 4 ring bufs x 12 KB

  const int tid  = threadIdx.x;
  const int w    = tid >> 6;          // 0..7
  const int lane = tid & 63;
  const int wm   = w >> 2;            // M half (128 rows)
  const int wn   = w & 3;             // N quarter-swath (48 cols)
  const int lm   = lane & 15;
  const int quad = lane >> 4;

  // bijective XCD swizzle; 512 blocks = 64 per XCD
  const int wgid = (blockIdx.x & 7) * 64 + ((int)blockIdx.x >> 3);
  const int bn   = (wgid & 15) * 192;   // 16 bn tiles
  const int bm   = (wgid >> 4) * 256;   // 32 bm tiles

  const int srow = lane >> 2;                        // 0..15 within chunk
  const int scol = ((lane & 3) ^ ((lane >> 3) & 3)) * 8;
  const int rsw  = (quad ^ ((lm >> 1) & 3)) * 8;

  f32x4 acc[8][3] = {};

  auto stage = [&](int T) {
    const int b4 = T & 3;
    const size_t k0 = (size_t)T * 32;
    bf16* ab = &As[b4 * 8192];
    bf16* wb = &Ws[b4 * 6144];
#pragma unroll
    for (int j = 0; j < 2; ++j) {
      int c = 2 * w + j;               // 16 A-chunks (256 rows)
      gl_lds16(A + (size_t)(bm + c * 16 + srow) * 1024 + k0 + scol,
               ab + c * 512);
    }
    if (w < 4) {
#pragma unroll
      for (int j = 0; j < 2; ++j) {
        int c = 2 * w + j;             // B-chunks 0..7 (rows 0..127)
        gl_lds16(W + (size_t)(bn + c * 16 + srow) * 1024 + k0 + scol,
                 wb + c * 512);
      }
    } else {
      int c = 8 + (w - 4);             // B-chunks 8..11 (rows 128..191)
      gl_lds16(W + (size_t)(bn + c * 16 + srow) * 1024 + k0 + scol,
               wb + c * 512);
    }
  };

#define RDFR(T1, FA, FB) do {                                                 \
    const bf16* ab_ = &As[((T1) & 3) * 8192];                                 \
    const bf16* wb_ = &Ws[((T1) & 3) * 6144];                                 \
    _Pragma("unroll") for (int mi = 0; mi < 8; ++mi)                          \
      FA[mi] = *reinterpret_cast<const bf16x8*>(                              \
          ab_ + (wm * 128 + mi * 16 + lm) * 32 + rsw);                        \
    _Pragma("unroll") for (int ni = 0; ni < 3; ++ni)                          \
      FB[ni] = *reinterpret_cast<const bf16x8*>(                              \
          wb_ + (wn * 48 + ni * 16 + lm) * 32 + rsw);                         \
  } while (0)

#define MM(FA, FB) do {                                                       \
    __builtin_amdgcn_s_setprio(1);                                            \
    _Pragma("unroll") for (int mi = 0; mi < 8; ++mi)                          \
      _Pragma("unroll") for (int ni = 0; ni < 3; ++ni)                        \
        acc[mi][ni] = MFMA16(FA[mi], FB[ni], acc[mi][ni]);                    \
    __builtin_amdgcn_s_setprio(0);                                            \
  } while (0)

  // per-wave stage issues/step: waves 0-3 -> 4, waves 4-7 -> 3
#define WAITN() do {                                                          \
    if (w < 4) asm volatile("s_waitcnt vmcnt(4)" ::: "memory");               \
    else       asm volatile("s_waitcnt vmcnt(3)" ::: "memory");               \
  } while (0)

  bf16x8 fa0[8], fa1[8];
  bf16x8 fb0[3], fb1[3];

  // prologue: stage steps 0..2; wait certifies steps 0 AND 1 (outstanding =
  // step 2's n); read step-0 frags.
  stage(0); stage(1); stage(2);
  WAITN();
  fbar();
  RDFR(0, fa0, fb0);

  // steady state: 32 K-steps total
  for (int t = 0; t < 28; t += 2) {
    stage(t + 3); RDFR(t + 1, fa1, fb1); MM(fa0, fb0); WAITN(); fbar();
    stage(t + 4); RDFR(t + 2, fa0, fb0); MM(fa1, fb1); WAITN(); fbar();
  }
  // t = 28 (stages the last step, 31)
  stage(31); RDFR(29, fa1, fb1); MM(fa0, fb0); WAITN(); fbar();
  // t = 29: certify step 31 (drain to 0)
  RDFR(30, fa0, fb0); MM(fa1, fb1);
  asm volatile("s_waitcnt vmcnt(0)" ::: "memory");
  fbar();
  // t = 30 (no further LDS writes -> no trailing barrier needed)
  RDFR(31, fa1, fb1); MM(fa0, fb0);
  // t = 31
  MM(fa1, fb1);

#undef RDFR
#undef MM
#undef WAITN

  // frag-tiled scatter epilogue (identical layout to verified kernel)
#pragma unroll
  for (int mi = 0; mi < 8; ++mi) {
#pragma unroll
    for (int r = 0; r < 4; ++r) {
      int row = bm + wm * 128 + mi * 16 + quad * 4 + r;
#pragma unroll
      for (int ni = 0; ni < 3; ++ni) {
        int col = bn + wn * 48 + ni * 16 + lm;
        float v = acc[mi][ni][r];
        int reg = col >> 10;            // 0=q, 1=k, 2=v
        int cc  = col & 1023;
        int bb  = row >> 11;            // N_ == 2048
        int n   = row & (N_ - 1);
        int hh  = cc >> 6;
        int dd  = cc & 63;
        if (reg < 2) {
          // F[bh][t32][s][hi][m][8]: d = 16s+8hi+j, m = n&31
          int t32 = n >> 5, m = n & 31;
          int s = dd >> 4, hb = (dd >> 3) & 1, j = dd & 7;
          Cv[(size_t)reg * MD_ +
             (size_t)(bb * H_ + hh) * BHSZ_ +
             (size_t)t32 * 2048 + s * 512 + hb * 256 + m * 8 + j] = f2b(v);
        } else {
          // Vf[bh][t32][hf][hi][hd][8]; key = 32*t32 + 16*hf + 8*hi + j
          int t32 = n >> 5, kk = n & 31;
          int hf = kk >> 4, hb = (kk >> 3) & 1, j = kk & 7;
          Cv[2 * MD_ +
             (size_t)(bb * H_ + hh) * BHSZ_ +
             (size_t)t32 * 2048 + hf * 1024 + hb * 512 + dd * 8 + j] = f2b(v);
        }
      }
    }
  }
}

// ---------------------------------------------------------------------------
// Output-projection GEMM (reverted to the round-0 VERIFIED structure):
// C[M,N] = A[M,K] @ W[N,K]^T + bias, fp32 out. 128x128 tile, BK=32, 4 waves.
// ---------------------------------------------------------------------------
__global__ __launch_bounds__(256) void pgemm(
    const bf16* __restrict__ A, const bf16* __restrict__ W,
    const float* __restrict__ bias, float* __restrict__ C,
    int M, int N, int K)
{
  __shared__ bf16 As[128 * 32];
  __shared__ bf16 Ws[128 * 32];

  const int tid  = threadIdx.x;
  const int w    = tid >> 6;
  const int lane = tid & 63;
  const int bm   = blockIdx.y * 128;
  const int bn   = blockIdx.x * 128;

  const int wr = (w >> 1) * 64;
  const int wc = (w & 1) * 64;
  const int lm   = lane & 15;
  const int quad = lane >> 4;

  const int srow = lane >> 2;
  const int sslot = (lane & 3) ^ ((lane >> 3) & 3);
  const int scol = sslot * 8;
  const int rsw  = (quad ^ ((lm >> 1) & 3)) * 8;

  f32x4 acc[4][4] = {};

  for (int k0 = 0; k0 < K; k0 += 32) {
#pragma unroll
    for (int cc = 0; cc < 2; ++cc) {
      int c = w * 2 + cc;
      int r = c * 16 + srow;
      gl_lds16(A + (size_t)(bm + r) * K + k0 + scol, &As[c * 512]);
      gl_lds16(W + (size_t)(bn + r) * K + k0 + scol, &Ws[c * 512]);
    }
    __syncthreads();

    bf16x8 af[4], bf_[4];
#pragma unroll
    for (int mi = 0; mi < 4; ++mi)
      af[mi] = *reinterpret_cast<const bf16x8*>(&As[(wr + mi * 16 + lm) * 32 + rsw]);
#pragma unroll
    for (int ni = 0; ni < 4; ++ni)
      bf_[ni] = *reinterpret_cast<const bf16x8*>(&Ws[(wc + ni * 16 + lm) * 32 + rsw]);

#pragma unroll
    for (int mi = 0; mi < 4; ++mi)
#pragma unroll
      for (int ni = 0; ni < 4; ++ni)
        acc[mi][ni] = __builtin_amdgcn_mfma_f32_16x16x32_bf16(
            af[mi], bf_[ni], acc[mi][ni], 0, 0, 0);
    __syncthreads();
  }

#pragma unroll
  for (int mi = 0; mi < 4; ++mi) {
#pragma unroll
    for (int r = 0; r < 4; ++r) {
      int row = bm + wr + mi * 16 + quad * 4 + r;
#pragma unroll
      for (int ni = 0; ni < 4; ++ni) {
        int col = bn + wc + ni * 16 + lm;
        float v = acc[mi][ni][r] + bias[col];
        C[(size_t)row * N + col] = v;
      }
    }
  }
}

// ---------------------------------------------------------------------------
// In-place RoPE on frag-tiled Q and K (one launch). Each thread owns one
// 16B block = (bh, t32, s, hi, m, j=0..7) -> 4 interleaved pairs, all with
// n = 32*t32 + m, i = 8s + 4hi + p. Fully coalesced 16B r/w.
// Q half additionally folds QSC_ (= SCALE * log2e).
// ---------------------------------------------------------------------------
__global__ __launch_bounds__(256) void rope_inplace(bf16* __restrict__ qf,
                                                    bf16* __restrict__ kf)
{
  const int half = blockIdx.x >> 12;        // 0 = q, 1 = k
  const int blk  = blockIdx.x & 4095;
  bf16* base = half ? kf : qf;
  const float LN_THETA = 9.210340371976184f;

  size_t e = ((size_t)blk * 256 + threadIdx.x) * 8;
  int within = (int)(e & (BHSZ_ - 1));
  int t32 = within >> 11;
  int rem = within & 2047;
  int s  = rem >> 9;
  int hb = (rem >> 8) & 1;
  int m  = (rem >> 3) & 31;
  int n  = t32 * 32 + m;

  uint4 raw = *reinterpret_cast<const uint4*>(base + e);
  unsigned int pr[4] = {raw.x, raw.y, raw.z, raw.w};
  unsigned int outw[4];
#pragma unroll
  for (int p = 0; p < 4; ++p) {
    int i = s * 8 + hb * 4 + p;
    float inv = __expf(-((float)(2 * i) / (float)HD_) * LN_THETA);
    float ang = (float)n * inv;
    float sv, cv;
    sincosf(ang, &sv, &cv);
    float a = b2f(((bf16*)&pr[p])[0]);
    float c = b2f(((bf16*)&pr[p])[1]);
    float r0 = a * cv - c * sv;
    float r1 = c * cv + a * sv;
    if (half == 0) { r0 *= QSC_; r1 *= QSC_; }
    outw[p] = pk2(r0, r1);
  }
  uint4 o = {outw[0], outw[1], outw[2], outw[3]};
  *reinterpret_cast<uint4*>(base + e) = o;
}

// ---------------------------------------------------------------------------
// Flash attention v4 (unchanged — verified): transpose formulation
// (S^T = K Q^T, O^T = V^T P^T, mfma_f32_32x32x16_bf16), shift-free softmax,
// 2-way key-split + LDS combine, frag-tiled operands.
// C/D: col=lane&31, row=(reg&3)+8*(reg>>2)+4*(lane>>5)  [m74/m101].
// ---------------------------------------------------------------------------
__global__ __launch_bounds__(128) void fattn4_kernel(
    const bf16* __restrict__ Qf, const bf16* __restrict__ Kf,
    const bf16* __restrict__ Vf, bf16* __restrict__ O)
{
  __shared__ float Ls[32 * 64];
  __shared__ float Ll[64];

  const int wv   = threadIdx.x >> 6;       // key-split half 0/1
  const int lane = threadIdx.x & 63;
  const int blk  = blockIdx.x;             // 0..4095
  const int xcd  = blk & 7;
  const int j    = blk >> 3;               // 0..511
  const int qt   = 63 - (j >> 3);          // big q-tiles dispatched first
  const int bh   = xcd * 8 + (j & 7);      // 8 bh per XCD group
  const int b    = bh >> 4;
  const int h    = bh & 15;
  const int col  = lane & 31;              // q-row / hd-row within frag
  const int hi   = lane >> 5;              // lane half

  const bf16* Qb = Qf + (size_t)bh * BHSZ_ + (size_t)qt * 2048 + hi * 256 + col * 8;
  const bf16* Kb = Kf + (size_t)bh * BHSZ_ + hi * 256 + col * 8;
  const bf16* Vb = Vf + (size_t)bh * BHSZ_ + hi * 512 + col * 8;

  bf16x8 qb[4];
#pragma unroll
  for (int s = 0; s < 4; ++s)
    qb[s] = *reinterpret_cast<const bf16x8*>(Qb + s * 512);

  f32x16 o0 = {}, o1 = {};
  float lsum = 0.f;

  for (int kst = wv; kst <= qt; kst += 2) {
    const bf16* kp = Kb + (size_t)kst * 2048;
    f32x16 st = {};
#pragma unroll
    for (int s = 0; s < 4; ++s) {
      bf16x8 ka = *reinterpret_cast<const bf16x8*>(kp + s * 512);
      st = __builtin_amdgcn_mfma_f32_32x32x16_bf16(ka, qb[s], st, 0, 0, 0);
    }

    float pe[16];
    if (kst == qt) {
#pragma unroll
      for (int r = 0; r < 16; ++r) {
        int koff = (r & 3) + 8 * (r >> 2) + 4 * hi;
        float e = (koff <= col) ? exp2f(st[r]) : 0.f;
        pe[r] = e; lsum += e;
      }
    } else {
#pragma unroll
      for (int r = 0; r < 16; ++r) {
        float e = exp2f(st[r]);
        pe[r] = e; lsum += e;
      }
    }

    const bf16* vp = Vb + (size_t)kst * 2048;
#pragma unroll
    for (int hf = 0; hf < 2; ++hf) {
      unsigned int a0 = pk2t(pe[8 * hf + 0], pe[8 * hf + 1]);
      unsigned int a1 = pk2t(pe[8 * hf + 2], pe[8 * hf + 3]);
      unsigned int b0 = pk2t(pe[8 * hf + 4], pe[8 * hf + 5]);
      unsigned int b1 = pk2t(pe[8 * hf + 6], pe[8 * hf + 7]);
      unsigned int s0 = hi ? a0 : b0;
      unsigned int s1 = hi ? a1 : b1;
      unsigned int r0 = (unsigned int)__shfl_xor((int)s0, 32);
      unsigned int r1 = (unsigned int)__shfl_xor((int)s1, 32);
      union { uint4 u; bf16x8 v; } pb;
      pb.u.x = hi ? r0 : a0;
      pb.u.y = hi ? r1 : a1;
      pb.u.z = hi ? b0 : r0;
      pb.u.w = hi ? b1 : r1;

      bf16x8 v0 = *reinterpret_cast<const bf16x8*>(vp + hf * 1024);
      bf16x8 v1 = *reinterpret_cast<const bf16x8*>(vp + hf * 1024 + 256);
      o0 = __builtin_amdgcn_mfma_f32_32x32x16_bf16(v0, pb.v, o0, 0, 0, 0);
      o1 = __builtin_amdgcn_mfma_f32_32x32x16_bf16(v1, pb.v, o1, 0, 0, 0);
    }
  }

  if (wv == 1) {
#pragma unroll
    for (int r = 0; r < 16; ++r) {
      Ls[r * 64 + lane]        = o0[r];
      Ls[(16 + r) * 64 + lane] = o1[r];
    }
    Ll[lane] = lsum;
  }
  __syncthreads();
  if (wv == 0) {
    float lt = lsum + Ll[lane];
    lt += __shfl_xor(lt, 32);
    float inv = 1.f / lt;
#pragma unroll
    for (int r = 0; r < 16; ++r) {
      o0[r] = (o0[r] + Ls[r * 64 + lane]) * inv;
      o1[r] = (o1[r] + Ls[(16 + r) * 64 + lane]) * inv;
    }
    bf16* Op = O + ((size_t)(b * N_ + 32 * qt + col)) * D_ + h * HD_;
#pragma unroll
    for (int g = 0; g < 4; ++g) {
      uint2 u;
      u.x = pk2(o0[4 * g + 0], o0[4 * g + 1]);
      u.y = pk2(o0[4 * g + 2], o0[4 * g + 3]);
      *reinterpret_cast<uint2*>(Op + 8 * g + 4 * hi) = u;
      u.x = pk2(o1[4 * g + 0], o1[4 * g + 1]);
      u.y = pk2(o1[4 * g + 2], o1[4 * g + 3]);
      *reinterpret_cast<uint2*>(Op + 32 + 8 * g + 4 * hi) = u;
    }
  }
}

// ---------------------------------------------------------------------------
extern "C" void kernel_launch(void* const* d_in, const int* in_sizes, int n_in,
                              void* d_out, int out_size, void* d_ws, size_t ws_size,
                              hipStream_t stream)
{
  const float* x  = (const float*)d_in[0];
  const float* Wq = (const float*)d_in[1];
  const float* Wk = (const float*)d_in[2];
  const float* Wv = (const float*)d_in[3];
  const float* Wo = (const float*)d_in[4];
  const float* bo = (const float*)d_in[5];
  float* out = (float*)d_out;

  const int M = B_ * N_;                    // 8192

  bf16* xb  = (bf16*)d_ws;                  // x bf16; dead after QKV -> ao
  bf16* qf  = xb + MD_;                     // Qf | Kf | Vf contiguous slabs
  bf16* kf  = qf + MD_;
  bf16* vf  = kf + MD_;
  bf16* Wqb = vf + MD_;                     // Wq|Wk|Wv|Wo bf16
  bf16* Wob = Wqb + 3 * DD_;
  bf16* ao  = xb;

  cvt_all<<<6144, 256, 0, stream>>>(x, Wq, Wk, Wv, Wo, xb, Wqb);

  // fused QKV: C[8192, 3072]; 32 x 16 = 512 blocks (2 exact CU rounds)
  qkv_ring<<<512, 512, 0, stream>>>(xb, Wqb, qf);

  // in-place RoPE on Qf (with QSC fold) and Kf: 2 * 4096 blocks
  rope_inplace<<<8192, 256, 0, stream>>>(qf, kf);

  // one block (2 key-split waves) per (bh, 32-row q-tile): 4096 blocks
  fattn4_kernel<<<4096, 128, 0, stream>>>(qf, kf, vf, ao);

  // output proj (verified 128^2 structure): 8 x 64 = 512 blocks
  pgemm<<<dim3(8, 64), 256, 0, stream>>>(ao, Wob, bo, out, M, D_, D_);
}

// Round 4
// 277.286 us; speedup vs baseline: 1.0481x; 1.0188x over previous
//
#include <hip/hip_runtime.h>
#include <hip/hip_bf16.h>
#include <math.h>

#define B_ 4
#define N_ 2048
#define D_ 1024
#define H_ 16
#define HD_ 64
#define SCALE_ 0.015625f   // 1/HD
#define MD_ ((size_t)B_ * N_ * D_)   // 8388608
#define DD_ ((size_t)D_ * D_)        // 1048576
#define BHSZ_ ((size_t)N_ * HD_)     // 131072 elems per (b,h) frag slab
// folded into q at RoPE: SCALE * log2(e)
#define QSC_ 0.0225421143f

typedef __hip_bfloat16 bf16;
typedef __attribute__((ext_vector_type(8))) __bf16 bf16x8;
typedef __attribute__((ext_vector_type(4))) float f32x4;
typedef __attribute__((ext_vector_type(16))) float f32x16;

__device__ __forceinline__ float b2f(bf16 x) { return __bfloat162float(x); }
__device__ __forceinline__ bf16 f2b(float x) { return __float2bfloat16(x); }

// exact (RNE) pack of two floats to bf16 pair (elem0 low)
__device__ __forceinline__ unsigned int pk2(float a, float b) {
  union { bf16 h[2]; unsigned int u; } t;
  t.h[0] = f2b(a); t.h[1] = f2b(b);
  return t.u;
}
// truncating pack (cheap; for P fragments only, e >= 0)
__device__ __forceinline__ unsigned int pk2t(float a, float b) {
  return (__float_as_uint(a) >> 16) | (__float_as_uint(b) & 0xffff0000u);
}

// async global->LDS, 16 bytes per lane
__device__ __forceinline__ void gl_lds16(const bf16* g, bf16* l) {
  __builtin_amdgcn_global_load_lds(
      (const __attribute__((address_space(1))) void*)g,
      (__attribute__((address_space(3))) void*)l, 16, 0, 0);
}

// ---------------------------------------------------------------------------
// Fused fp32 -> bf16 conversion of x, Wq, Wk, Wv, Wo, PLUS RoPE cos/sin
// table generation (blocks 6144..6207): rt[n*32 + i] = (cos, sin) of
// n * theta^(-i/32), 2048x32 float2 = 512 KB. Same math as the old
// rope_inplace kernel (exp/sincos bit-identical inputs).
// ---------------------------------------------------------------------------
__global__ __launch_bounds__(256) void cvt_all(
    const float* __restrict__ x,  const float* __restrict__ wq,
    const float* __restrict__ wk, const float* __restrict__ wv,
    const float* __restrict__ wo, bf16* __restrict__ xb,
    bf16* __restrict__ wb, float2* __restrict__ rt)
{
  const int blk = blockIdx.x;
  if (blk >= 6144) {
    const float LN_THETA = 9.210340371976184f;
    int e = ((blk - 6144) * 256 + (int)threadIdx.x) * 4;
    float fn = (float)(e >> 5);
#pragma unroll
    for (int p = 0; p < 4; ++p) {
      int i = (e & 31) + p;
      float inv = __expf(-((float)(2 * i) / (float)HD_) * LN_THETA);
      float sv, cv;
      sincosf(fn * inv, &sv, &cv);
      rt[e + p] = make_float2(cv, sv);
    }
    return;
  }
  const float* s; bf16* d; int i;
  if (blk < 4096)      { s = x;  d = xb;           i = blk; }
  else if (blk < 4608) { s = wq; d = wb;           i = blk - 4096; }
  else if (blk < 5120) { s = wk; d = wb + DD_;     i = blk - 4608; }
  else if (blk < 5632) { s = wv; d = wb + 2 * DD_; i = blk - 5120; }
  else                 { s = wo; d = wb + 3 * DD_; i = blk - 5632; }
  int e = (i * 256 + threadIdx.x) * 8;
  float4 a = *reinterpret_cast<const float4*>(s + e);
  float4 b = *reinterpret_cast<const float4*>(s + e + 4);
  bf16 t[8] = {f2b(a.x), f2b(a.y), f2b(a.z), f2b(a.w),
               f2b(b.x), f2b(b.y), f2b(b.z), f2b(b.w)};
  *reinterpret_cast<int4*>(d + e) = *reinterpret_cast<const int4*>(t);
}

// ---------------------------------------------------------------------------
// MFMA GEMM (round-0 VERIFIED structure): C[M,N] = A[M,K] @ W[N,K]^T,
// bf16 in, fp32 accumulate. 128x128 tile, BK=32, 4 waves 2x2, 4x4
// mfma_f32_16x16x32_bf16 per wave. Staging via global_load_lds width=16 with
// the XOR chunk swizzle (2-way bank aliasing = free; SQ_LDS_BANK_CONFLICT=0).
//
// MODE 0: fused QKV epilogue, frag-tiled Q/K/V — WITH FUSED RoPE:
//   thread's col pairs with col^1 which lives in lane^1 (same acc index), so
//   one __shfl_xor(v,1) + a table float2 gives the rotation. reg<2 is
//   wave-uniform per ni (16-col chunks never straddle the 1024 boundary).
//   Q additionally folds QSC_ (= SCALE * log2e) as before.
// MODE 1: fp32 output + bias.
// ---------------------------------------------------------------------------
template <int MODE>
__global__ __launch_bounds__(256) void mgemm(
    const bf16* __restrict__ A, const bf16* __restrict__ W,
    const float* __restrict__ bias, void* __restrict__ Cv,
    const float2* __restrict__ rt, int M, int N, int K)
{
  __shared__ bf16 As[128 * 32];
  __shared__ bf16 Ws[128 * 32];

  const int tid  = threadIdx.x;
  const int w    = tid >> 6;
  const int lane = tid & 63;
  const int bm   = blockIdx.y * 128;
  const int bn   = blockIdx.x * 128;

  const int wr = (w >> 1) * 64;
  const int wc = (w & 1) * 64;
  const int lm   = lane & 15;
  const int quad = lane >> 4;

  // staging: r = lane>>2 within chunk, swizzled global slot
  const int srow = lane >> 2;                        // 0..15
  const int sslot = (lane & 3) ^ ((lane >> 3) & 3);  // global slot fetched
  const int scol = sslot * 8;

  // reader swizzle: logical slot quad of row lm -> phys slot
  const int rsw  = (quad ^ ((lm >> 1) & 3)) * 8;

  f32x4 acc[4][4] = {};

  for (int k0 = 0; k0 < K; k0 += 32) {
#pragma unroll
    for (int cc = 0; cc < 2; ++cc) {
      int c = w * 2 + cc;
      int r = c * 16 + srow;
      gl_lds16(A + (size_t)(bm + r) * K + k0 + scol, &As[c * 512]);
      gl_lds16(W + (size_t)(bn + r) * K + k0 + scol, &Ws[c * 512]);
    }
    __syncthreads();

    bf16x8 af[4], bf_[4];
#pragma unroll
    for (int mi = 0; mi < 4; ++mi)
      af[mi] = *reinterpret_cast<const bf16x8*>(&As[(wr + mi * 16 + lm) * 32 + rsw]);
#pragma unroll
    for (int ni = 0; ni < 4; ++ni)
      bf_[ni] = *reinterpret_cast<const bf16x8*>(&Ws[(wc + ni * 16 + lm) * 32 + rsw]);

#pragma unroll
    for (int mi = 0; mi < 4; ++mi)
#pragma unroll
      for (int ni = 0; ni < 4; ++ni)
        acc[mi][ni] = __builtin_amdgcn_mfma_f32_16x16x32_bf16(
            af[mi], bf_[ni], acc[mi][ni], 0, 0, 0);
    __syncthreads();
  }

#pragma unroll
  for (int mi = 0; mi < 4; ++mi) {
#pragma unroll
    for (int r = 0; r < 4; ++r) {
      int row = bm + wr + mi * 16 + quad * 4 + r;
#pragma unroll
      for (int ni = 0; ni < 4; ++ni) {
        int col = bn + wc + ni * 16 + lm;
        float v = acc[mi][ni][r];
        if (MODE == 1) {
          v += bias[col];
          reinterpret_cast<float*>(Cv)[(size_t)row * N + col] = v;
        } else {
          int reg = col >> 10;            // 0=q, 1=k, 2=v
          int cc  = col & 1023;
          int bb  = row >> 11;            // N_ == 2048
          int n   = row & (N_ - 1);
          int hh  = cc >> 6;
          int dd  = cc & 63;
          // partner value for RoPE (col^1 == lane^1, same acc slot);
          // harmless for the v region.
          float po = __shfl_xor(v, 1);
          if (reg < 2) {
            // fused RoPE: out[2i]   = v*cos - v_odd*sin
            //             out[2i+1] = v*cos + v_even*sin
            float2 cs = rt[(n << 5) + (dd >> 1)];
            v = (dd & 1) ? (v * cs.x + po * cs.y)
                         : (v * cs.x - po * cs.y);
            if (reg == 0) v *= QSC_;
            // frag-tiled F[bh][t32][s][hi][m][8]: d = 16s+8hi+j, m = n&31
            int t32 = n >> 5, m = n & 31;
            int s = dd >> 4, hb = (dd >> 3) & 1, j = dd & 7;
            reinterpret_cast<bf16*>(Cv)[(size_t)reg * MD_ +
                (size_t)(bb * H_ + hh) * BHSZ_ +
                (size_t)t32 * 2048 + s * 512 + hb * 256 + m * 8 + j] = f2b(v);
          } else {
            // Vf[bh][t32][hf][hi][hd][8]; key = 32*t32 + 16*hf + 8*hi + j
            int t32 = n >> 5, kk = n & 31;
            int hf = kk >> 4, hb = (kk >> 3) & 1, j = kk & 7;
            reinterpret_cast<bf16*>(Cv)[2 * MD_ +
                (size_t)(bb * H_ + hh) * BHSZ_ +
                (size_t)t32 * 2048 + hf * 1024 + hb * 512 + dd * 8 + j] = f2b(v);
          }
        }
      }
    }
  }
}

// ---------------------------------------------------------------------------
// Flash attention v4 (unchanged — verified): transpose formulation
// (S^T = K Q^T, O^T = V^T P^T, mfma_f32_32x32x16_bf16), shift-free softmax,
// 2-way key-split + LDS combine, frag-tiled operands.
// C/D: col=lane&31, row=(reg&3)+8*(reg>>2)+4*(lane>>5)  [m74/m101].
// ---------------------------------------------------------------------------
__global__ __launch_bounds__(128) void fattn4_kernel(
    const bf16* __restrict__ Qf, const bf16* __restrict__ Kf,
    const bf16* __restrict__ Vf, bf16* __restrict__ O)
{
  __shared__ float Ls[32 * 64];
  __shared__ float Ll[64];

  const int wv   = threadIdx.x >> 6;       // key-split half 0/1
  const int lane = threadIdx.x & 63;
  const int blk  = blockIdx.x;             // 0..4095
  const int xcd  = blk & 7;
  const int j    = blk >> 3;               // 0..511
  const int qt   = 63 - (j >> 3);          // big q-tiles dispatched first
  const int bh   = xcd * 8 + (j & 7);      // 8 bh per XCD group
  const int b    = bh >> 4;
  const int h    = bh & 15;
  const int col  = lane & 31;              // q-row / hd-row within frag
  const int hi   = lane >> 5;              // lane half

  const bf16* Qb = Qf + (size_t)bh * BHSZ_ + (size_t)qt * 2048 + hi * 256 + col * 8;
  const bf16* Kb = Kf + (size_t)bh * BHSZ_ + hi * 256 + col * 8;
  const bf16* Vb = Vf + (size_t)bh * BHSZ_ + hi * 512 + col * 8;

  bf16x8 qb[4];
#pragma unroll
  for (int s = 0; s < 4; ++s)
    qb[s] = *reinterpret_cast<const bf16x8*>(Qb + s * 512);

  f32x16 o0 = {}, o1 = {};
  float lsum = 0.f;

  for (int kst = wv; kst <= qt; kst += 2) {
    const bf16* kp = Kb + (size_t)kst * 2048;
    f32x16 st = {};
#pragma unroll
    for (int s = 0; s < 4; ++s) {
      bf16x8 ka = *reinterpret_cast<const bf16x8*>(kp + s * 512);
      st = __builtin_amdgcn_mfma_f32_32x32x16_bf16(ka, qb[s], st, 0, 0, 0);
    }

    float pe[16];
    if (kst == qt) {
#pragma unroll
      for (int r = 0; r < 16; ++r) {
        int koff = (r & 3) + 8 * (r >> 2) + 4 * hi;
        float e = (koff <= col) ? exp2f(st[r]) : 0.f;
        pe[r] = e; lsum += e;
      }
    } else {
#pragma unroll
      for (int r = 0; r < 16; ++r) {
        float e = exp2f(st[r]);
        pe[r] = e; lsum += e;
      }
    }

    const bf16* vp = Vb + (size_t)kst * 2048;
#pragma unroll
    for (int hf = 0; hf < 2; ++hf) {
      unsigned int a0 = pk2t(pe[8 * hf + 0], pe[8 * hf + 1]);
      unsigned int a1 = pk2t(pe[8 * hf + 2], pe[8 * hf + 3]);
      unsigned int b0 = pk2t(pe[8 * hf + 4], pe[8 * hf + 5]);
      unsigned int b1 = pk2t(pe[8 * hf + 6], pe[8 * hf + 7]);
      unsigned int s0 = hi ? a0 : b0;
      unsigned int s1 = hi ? a1 : b1;
      unsigned int r0 = (unsigned int)__shfl_xor((int)s0, 32);
      unsigned int r1 = (unsigned int)__shfl_xor((int)s1, 32);
      union { uint4 u; bf16x8 v; } pb;
      pb.u.x = hi ? r0 : a0;
      pb.u.y = hi ? r1 : a1;
      pb.u.z = hi ? b0 : r0;
      pb.u.w = hi ? b1 : r1;

      bf16x8 v0 = *reinterpret_cast<const bf16x8*>(vp + hf * 1024);
      bf16x8 v1 = *reinterpret_cast<const bf16x8*>(vp + hf * 1024 + 256);
      o0 = __builtin_amdgcn_mfma_f32_32x32x16_bf16(v0, pb.v, o0, 0, 0, 0);
      o1 = __builtin_amdgcn_mfma_f32_32x32x16_bf16(v1, pb.v, o1, 0, 0, 0);
    }
  }

  if (wv == 1) {
#pragma unroll
    for (int r = 0; r < 16; ++r) {
      Ls[r * 64 + lane]        = o0[r];
      Ls[(16 + r) * 64 + lane] = o1[r];
    }
    Ll[lane] = lsum;
  }
  __syncthreads();
  if (wv == 0) {
    float lt = lsum + Ll[lane];
    lt += __shfl_xor(lt, 32);
    float inv = 1.f / lt;
#pragma unroll
    for (int r = 0; r < 16; ++r) {
      o0[r] = (o0[r] + Ls[r * 64 + lane]) * inv;
      o1[r] = (o1[r] + Ls[(16 + r) * 64 + lane]) * inv;
    }
    bf16* Op = O + ((size_t)(b * N_ + 32 * qt + col)) * D_ + h * HD_;
#pragma unroll
    for (int g = 0; g < 4; ++g) {
      uint2 u;
      u.x = pk2(o0[4 * g + 0], o0[4 * g + 1]);
      u.y = pk2(o0[4 * g + 2], o0[4 * g + 3]);
      *reinterpret_cast<uint2*>(Op + 8 * g + 4 * hi) = u;
      u.x = pk2(o1[4 * g + 0], o1[4 * g + 1]);
      u.y = pk2(o1[4 * g + 2], o1[4 * g + 3]);
      *reinterpret_cast<uint2*>(Op + 32 + 8 * g + 4 * hi) = u;
    }
  }
}

// ---------------------------------------------------------------------------
extern "C" void kernel_launch(void* const* d_in, const int* in_sizes, int n_in,
                              void* d_out, int out_size, void* d_ws, size_t ws_size,
                              hipStream_t stream)
{
  const float* x  = (const float*)d_in[0];
  const float* Wq = (const float*)d_in[1];
  const float* Wk = (const float*)d_in[2];
  const float* Wv = (const float*)d_in[3];
  const float* Wo = (const float*)d_in[4];
  const float* bo = (const float*)d_in[5];
  float* out = (float*)d_out;

  const int M = B_ * N_;                    // 8192

  bf16* xb  = (bf16*)d_ws;                  // x bf16; dead after QKV -> ao
  bf16* qf  = xb + MD_;                     // Qf | Kf | Vf contiguous slabs
  bf16* kf  = qf + MD_;
  bf16* vf  = kf + MD_;
  bf16* Wqb = vf + MD_;                     // Wq|Wk|Wv|Wo bf16
  bf16* Wob = Wqb + 3 * DD_;
  float2* rt = (float2*)(Wqb + 4 * DD_);    // RoPE table: 2048x32 float2, 512 KB
  bf16* ao  = xb;

  // conversions + RoPE table (64 extra blocks)
  cvt_all<<<6208, 256, 0, stream>>>(x, Wq, Wk, Wv, Wo, xb, Wqb, rt);

  // fused QKV + RoPE: C[8192, 3072] vs [Wq;Wk;Wv]; writes roped Qf,Kf + Vf
  mgemm<0><<<dim3(24, 64), 256, 0, stream>>>(xb, Wqb, nullptr, qf, rt, M, 3 * D_, D_);

  // one block (2 key-split waves) per (bh, 32-row q-tile): 4096 blocks
  fattn4_kernel<<<4096, 128, 0, stream>>>(qf, kf, vf, ao);

  // output proj
  mgemm<1><<<dim3(8, 64), 256, 0, stream>>>(ao, Wob, bo, out, nullptr, M, D_, D_);
}